// Round 7
// baseline (287.156 us; speedup 1.0000x reference)
//
#include <hip/hip_runtime.h>
#include <hip/hip_fp16.h>

#define NWIN 4096
#define EPSF 1e-6f
#define GRID_SEG 512
#define BLOCK_SEG 512

// fixed-point scales (u32 LDS atomics; native ds_add_u32)
#define SCALE_P   2097152.0f     // 2^21  sum_p   (<=1150*2^21 = 2.4e9 < 4.29e9)
#define SCALE_R   131072.0f      // 2^17  agg_rate / sum_pd
#define INV_P     (1.0/2097152.0)
#define INV_R     (1.0/131072.0)
#define SCALE_CE  1048576.0f     // 2^20  CE num/den (scales cancel in the ratio)

// ---------------- workspace layout (bytes) ----------------
//  byte 0:  u64 ce_num        byte 8:  u64 ce_den
//  byte 16: u32 n_valid(u[4]) byte 20: u32 n_mask(u[5])
//  byte 24: f32 ref_dobs(f[6]) byte 28: f32 frac(f[7])
//  byte 32,36: u32 prefixes (u[8],u[9])  byte 40,44: u32 ranks (u[10],u[11])
#define OFF_SEG   256            // float g_seg[16384]  interleaved [wi*4+c]
#define OFF_H1    65792          // u32[2048]
#define OFF_H2    73984          // u32[2*2048]
#define OFF_H3    90368          // u32[2*1024]
#define OFF_SEGU  131072         // u32 g_seg_u32[16384] interleaved
#define OFF_PART  262144         // GRID_SEG x 64KB u32 partials; keys; recs

__device__ __forceinline__ unsigned make_key_raw(const float4* __restrict__ xraw,
                                                 const int* __restrict__ mask,
                                                 const int* __restrict__ widx, int i)
{
    int wi = widx[i];
    int m = mask[i];
    if (wi < 0 || !m) return 0x7F800000u;
    float d = fmaxf(xraw[i].z, 0.0f);
    unsigned k = __float_as_uint(d);
    return (k == 0x80000000u) ? 0u : k;
}

// ---------------- pass 1: CE + keys + recs + hist1 (pure streaming) ----------------
__device__ __forceinline__ void ce_elem(
    float lgx, float lgy, int yi, int mi, float xz, float xw, int wi,
    float cw0, float cw1, unsigned* keyOut, unsigned long long* recOut,
    float& num, float& den, unsigned& nv, unsigned& nm, unsigned& zc,
    unsigned* s_h1)
{
    float wy = yi ? cw1 : cw0;
    float mx = fmaxf(lgx, lgy);
    float lse = mx + __logf(__expf(lgx - mx) + __expf(lgy - mx));
    float nll = lse - (yi ? lgy : lgx);
    if (mi) { nm++; num += wy * nll; den += wy; }

    bool vq = (wi >= 0) && mi;
    unsigned key = 0x7F800000u;
    if (vq) {
        nv++;
        float d = fmaxf(xz, 0.0f);
        key = __float_as_uint(d);
        if (key == 0x80000000u) key = 0u;
    }
    *keyOut = key;

    if (key == 0u) zc++;
    else atomicAdd(&s_h1[key >> 21], 1u);

    unsigned long long rec = 0xFFFFull;
    if (vq && (unsigned)wi < NWIN) {
        float p = 1.0f / (1.0f + __expf(lgx - lgy));
        float rate = fmaxf(xw, 0.0f);
        float dob  = fmaxf(xz, 0.0f);
        unsigned short hp  = __half_as_ushort(__float2half(p));
        unsigned short hpr = __half_as_ushort(__float2half(p * rate));
        unsigned short hpd = __half_as_ushort(__float2half(p * dob));
        rec = (unsigned long long)(unsigned short)wi
            | ((unsigned long long)hp  << 16)
            | ((unsigned long long)hpr << 32)
            | ((unsigned long long)hpd << 48);
    }
    *recOut = rec;
}

extern "C" __global__ __launch_bounds__(256)
void k_ce_keys(const float2* __restrict__ logits, const int* __restrict__ y,
               const int* __restrict__ mask, const float4* __restrict__ xraw,
               const int* __restrict__ widx, const float* __restrict__ cw,
               unsigned long long* __restrict__ ws_u64, unsigned* __restrict__ ws_u,
               unsigned* __restrict__ keys, unsigned long long* __restrict__ recs,
               unsigned* __restrict__ gh1, int use_keys, int use_rec, int n)
{
    __shared__ unsigned s_h1[2048];
    for (int j = threadIdx.x; j < 2048; j += 256) s_h1[j] = 0u;
    __syncthreads();

    const float cw0 = cw[0], cw1 = cw[1];
    float num = 0.0f, den = 0.0f;
    unsigned nv = 0u, nm = 0u, zc = 0u;

    const int nth = gridDim.x * blockDim.x;
    const int gtid = blockIdx.x * blockDim.x + threadIdx.x;
    const int nq = n >> 2;

    const float4* lg4 = (const float4*)logits;
    const int4* y4p = (const int4*)y;
    const int4* m4p = (const int4*)mask;
    const int4* w4p = (const int4*)widx;

    for (int q = gtid; q < nq; q += nth) {
        float4 lgA = lg4[2 * q], lgB = lg4[2 * q + 1];
        int4 y4 = y4p[q], m4 = m4p[q], w4 = w4p[q];
        float4 x0 = xraw[4 * q], x1 = xraw[4 * q + 1];
        float4 x2 = xraw[4 * q + 2], x3 = xraw[4 * q + 3];

        uint4 kq;
        unsigned long long r0, r1, r2, r3;
        ce_elem(lgA.x, lgA.y, y4.x, m4.x, x0.z, x0.w, w4.x, cw0, cw1,
                &kq.x, &r0, num, den, nv, nm, zc, s_h1);
        ce_elem(lgA.z, lgA.w, y4.y, m4.y, x1.z, x1.w, w4.y, cw0, cw1,
                &kq.y, &r1, num, den, nv, nm, zc, s_h1);
        ce_elem(lgB.x, lgB.y, y4.z, m4.z, x2.z, x2.w, w4.z, cw0, cw1,
                &kq.z, &r2, num, den, nv, nm, zc, s_h1);
        ce_elem(lgB.z, lgB.w, y4.w, m4.w, x3.z, x3.w, w4.w, cw0, cw1,
                &kq.w, &r3, num, den, nv, nm, zc, s_h1);
        if (use_keys) ((uint4*)keys)[q] = kq;
        if (use_rec) {
            ((ulonglong2*)recs)[2 * q]     = make_ulonglong2(r0, r1);
            ((ulonglong2*)recs)[2 * q + 1] = make_ulonglong2(r2, r3);
        }
    }
    for (int i = (nq << 2) + gtid; i < n; i += nth) {   // tail (n%4)
        float2 lg = logits[i];
        float4 xr = xraw[i];
        unsigned k;
        unsigned long long r;
        ce_elem(lg.x, lg.y, y[i], mask[i], xr.z, xr.w, widx[i], cw0, cw1,
                &k, &r, num, den, nv, nm, zc, s_h1);
        if (use_keys) keys[i] = k;
        if (use_rec) recs[i] = r;
    }

    for (int off = 32; off > 0; off >>= 1) {
        num += __shfl_down(num, off);
        den += __shfl_down(den, off);
        nv  += __shfl_down(nv, off);
        nm  += __shfl_down(nm, off);
        zc  += __shfl_down(zc, off);
    }
    if ((threadIdx.x & 63) == 0) {
        atomicAdd(&ws_u64[0], (unsigned long long)(num * SCALE_CE + 0.5f));
        atomicAdd(&ws_u64[1], (unsigned long long)(den * SCALE_CE + 0.5f));
        atomicAdd(&ws_u[4], nv);
        atomicAdd(&ws_u[5], nm);
        if (zc) atomicAdd(&s_h1[0], zc);
    }
    __syncthreads();
    for (int j = threadIdx.x; j < 2048; j += 256) {
        unsigned v = s_h1[j];
        if (v) atomicAdd(&gh1[j], v);
    }
}

// ---------------- pass 2: segment sums from 8B records ----------------
__device__ __forceinline__ void seg_rec(unsigned long long r, unsigned* s_seg)
{
    unsigned lo = (unsigned)r, hi = (unsigned)(r >> 32);
    unsigned w16 = lo & 0xFFFFu;
    if (w16 != 0xFFFFu) {
        float p  = __half2float(__ushort_as_half((unsigned short)(lo >> 16)));
        float pr = __half2float(__ushort_as_half((unsigned short)(hi & 0xFFFFu)));
        float pd = __half2float(__ushort_as_half((unsigned short)(hi >> 16)));
        unsigned b = w16 << 2;                 // interleaved: 4 different banks
        atomicAdd(&s_seg[b], 1u);
        atomicAdd(&s_seg[b + 1], (unsigned)(p  * SCALE_P + 0.5f));
        atomicAdd(&s_seg[b + 2], (unsigned)(pr * SCALE_R + 0.5f));
        atomicAdd(&s_seg[b + 3], (unsigned)(pd * SCALE_R + 0.5f));
    }
}

__device__ __forceinline__ void seg_raw(const float2* lg_, const int* mask,
                                        const int* widx, const float4* xraw,
                                        int i, unsigned* s_seg)
{
    int wi = widx[i];
    int m = mask[i];
    if (m && (unsigned)wi < NWIN) {
        float2 lg = lg_[i];
        float4 xr = xraw[i];
        float p = 1.0f / (1.0f + __expf(lg.x - lg.y));
        float rate = fmaxf(xr.w, 0.0f);
        float dob  = fmaxf(xr.z, 0.0f);
        unsigned b = (unsigned)wi << 2;
        atomicAdd(&s_seg[b], 1u);
        atomicAdd(&s_seg[b + 1], (unsigned)(p * SCALE_P + 0.5f));
        atomicAdd(&s_seg[b + 2], (unsigned)(p * rate * SCALE_R + 0.5f));
        atomicAdd(&s_seg[b + 3], (unsigned)(p * dob  * SCALE_R + 0.5f));
    }
}

extern "C" __global__ __launch_bounds__(BLOCK_SEG)
void k_seg(const unsigned long long* __restrict__ recs,
           const float2* __restrict__ logits, const int* __restrict__ mask,
           const float4* __restrict__ xraw, const int* __restrict__ widx,
           unsigned* __restrict__ part, unsigned* __restrict__ g_seg_u32,
           int use_part, int use_rec, int n)
{
    __shared__ unsigned s_seg[4 * NWIN];   // 64 KB interleaved [wi*4+c]
    for (int j = threadIdx.x; j < 4 * NWIN; j += BLOCK_SEG) s_seg[j] = 0u;
    __syncthreads();

    const int nth = GRID_SEG * BLOCK_SEG;
    const int gtid = blockIdx.x * BLOCK_SEG + threadIdx.x;

    if (use_rec) {
        const ulonglong2* r2 = (const ulonglong2*)recs;
        const int np = n >> 1;               // pairs
        int j = gtid;
        for (; j + nth < np; j += 2 * nth) { // 2 loads in flight
            ulonglong2 a = r2[j];
            ulonglong2 b = r2[j + nth];
            seg_rec(a.x, s_seg); seg_rec(a.y, s_seg);
            seg_rec(b.x, s_seg); seg_rec(b.y, s_seg);
        }
        for (; j < np; j += nth) {
            ulonglong2 a = r2[j];
            seg_rec(a.x, s_seg); seg_rec(a.y, s_seg);
        }
        if ((n & 1) && gtid == 0) seg_rec(recs[n - 1], s_seg);
    } else {
        for (int i = gtid; i < n; i += nth)
            seg_raw(logits, mask, widx, xraw, i, s_seg);
    }
    __syncthreads();

    if (use_part) {
        uint4* dst = (uint4*)(part + (size_t)blockIdx.x * (4 * NWIN));
        const uint4* src = (const uint4*)s_seg;
        for (int j = threadIdx.x; j < NWIN; j += BLOCK_SEG) dst[j] = src[j];
    } else {
        for (int j = threadIdx.x; j < 4 * NWIN; j += BLOCK_SEG) {
            unsigned v = s_seg[j];
            if (v) atomicAdd(&g_seg_u32[j], v);
        }
    }
}

// ---------------- partial reduction: 512 u32 partials -> g_seg_u32 ----------------
extern "C" __global__ __launch_bounds__(256)
void k_reduce(const unsigned* __restrict__ part, unsigned* __restrict__ g_seg_u32)
{
    const int bin = (blockIdx.x & 63) * 256 + threadIdx.x;
    const int c = blockIdx.x >> 6;
    const unsigned* p = part + (size_t)c * (GRID_SEG / 4) * (4 * NWIN) + bin;
    unsigned s = 0u;
#pragma unroll 8
    for (int b = 0; b < GRID_SEG / 4; ++b) s += p[(size_t)b * (4 * NWIN)];
    if (s) atomicAdd(&g_seg_u32[bin], s);
}

// convert u32 fixed-point sums to float g_seg (interleaved)
extern "C" __global__ __launch_bounds__(256)
void k_convert(const unsigned* __restrict__ gsu, float* __restrict__ g_seg)
{
    const int j = blockIdx.x * 256 + threadIdx.x;   // grid 64
    const int c = j & 3;
    double inv = (c == 0) ? 1.0 : (c == 1) ? INV_P : INV_R;
    g_seg[j] = (float)((double)gsu[j] * inv);
}

// ---------------- histogram passes 2 and 3 ----------------
__device__ __forceinline__ void h2_one(unsigned key, unsigned p0, unsigned p1,
                                       unsigned* h)
{
    unsigned top = key >> 21;
    unsigned sub = (key >> 10) & 2047u;
    if (top == p0) atomicAdd(&h[sub], 1u);
    if (top == p1) atomicAdd(&h[2048 + sub], 1u);
}

extern "C" __global__ __launch_bounds__(256)
void k_hist2(const unsigned* __restrict__ keys, const float4* __restrict__ xraw,
             const int* __restrict__ mask, const int* __restrict__ widx,
             int use_keys, int n, const unsigned* __restrict__ ws_u,
             unsigned* __restrict__ gh)
{
    __shared__ unsigned h[2 * 2048];
    for (int j = threadIdx.x; j < 2 * 2048; j += 256) h[j] = 0u;
    __syncthreads();
    const unsigned p0 = ws_u[8], p1 = ws_u[9];
    const int nthr = gridDim.x * blockDim.x;
    const int gtid = blockIdx.x * blockDim.x + threadIdx.x;
    const int nq = n >> 2;
    if (use_keys) {
        const uint4* k4 = (const uint4*)keys;
        int base = gtid;
        for (; base + 3 * nthr < nq; base += 4 * nthr) {
            uint4 a = k4[base], b = k4[base + nthr];
            uint4 c = k4[base + 2 * nthr], d = k4[base + 3 * nthr];
            h2_one(a.x, p0, p1, h); h2_one(a.y, p0, p1, h);
            h2_one(a.z, p0, p1, h); h2_one(a.w, p0, p1, h);
            h2_one(b.x, p0, p1, h); h2_one(b.y, p0, p1, h);
            h2_one(b.z, p0, p1, h); h2_one(b.w, p0, p1, h);
            h2_one(c.x, p0, p1, h); h2_one(c.y, p0, p1, h);
            h2_one(c.z, p0, p1, h); h2_one(c.w, p0, p1, h);
            h2_one(d.x, p0, p1, h); h2_one(d.y, p0, p1, h);
            h2_one(d.z, p0, p1, h); h2_one(d.w, p0, p1, h);
        }
        for (; base < nq; base += nthr) {
            uint4 a = k4[base];
            h2_one(a.x, p0, p1, h); h2_one(a.y, p0, p1, h);
            h2_one(a.z, p0, p1, h); h2_one(a.w, p0, p1, h);
        }
        for (int i = (nq << 2) + gtid; i < n; i += nthr)
            h2_one(keys[i], p0, p1, h);
    } else {
        for (int i = gtid; i < n; i += nthr)
            h2_one(make_key_raw(xraw, mask, widx, i), p0, p1, h);
    }
    __syncthreads();
    for (int j = threadIdx.x; j < 2 * 2048; j += 256)
        if (h[j]) atomicAdd(&gh[j], h[j]);
}

__device__ __forceinline__ void h3_one(unsigned key, unsigned p0, unsigned p1,
                                       unsigned* h)
{
    unsigned top = key >> 10;
    unsigned sub = key & 1023u;
    if (top == p0) atomicAdd(&h[sub], 1u);
    if (top == p1) atomicAdd(&h[1024 + sub], 1u);
}

extern "C" __global__ __launch_bounds__(256)
void k_hist3(const unsigned* __restrict__ keys, const float4* __restrict__ xraw,
             const int* __restrict__ mask, const int* __restrict__ widx,
             int use_keys, int n, const unsigned* __restrict__ ws_u,
             unsigned* __restrict__ gh)
{
    __shared__ unsigned h[2 * 1024];
    for (int j = threadIdx.x; j < 2 * 1024; j += 256) h[j] = 0u;
    __syncthreads();
    const unsigned p0 = ws_u[8], p1 = ws_u[9];
    const int nthr = gridDim.x * blockDim.x;
    const int gtid = blockIdx.x * blockDim.x + threadIdx.x;
    const int nq = n >> 2;
    if (use_keys) {
        const uint4* k4 = (const uint4*)keys;
        int base = gtid;
        for (; base + 3 * nthr < nq; base += 4 * nthr) {
            uint4 a = k4[base], b = k4[base + nthr];
            uint4 c = k4[base + 2 * nthr], d = k4[base + 3 * nthr];
            h3_one(a.x, p0, p1, h); h3_one(a.y, p0, p1, h);
            h3_one(a.z, p0, p1, h); h3_one(a.w, p0, p1, h);
            h3_one(b.x, p0, p1, h); h3_one(b.y, p0, p1, h);
            h3_one(b.z, p0, p1, h); h3_one(b.w, p0, p1, h);
            h3_one(c.x, p0, p1, h); h3_one(c.y, p0, p1, h);
            h3_one(c.z, p0, p1, h); h3_one(c.w, p0, p1, h);
            h3_one(d.x, p0, p1, h); h3_one(d.y, p0, p1, h);
            h3_one(d.z, p0, p1, h); h3_one(d.w, p0, p1, h);
        }
        for (; base < nq; base += nthr) {
            uint4 a = k4[base];
            h3_one(a.x, p0, p1, h); h3_one(a.y, p0, p1, h);
            h3_one(a.z, p0, p1, h); h3_one(a.w, p0, p1, h);
        }
        for (int i = (nq << 2) + gtid; i < n; i += nthr)
            h3_one(keys[i], p0, p1, h);
    } else {
        for (int i = gtid; i < n; i += nthr)
            h3_one(make_key_raw(xraw, mask, widx, i), p0, p1, h);
    }
    __syncthreads();
    for (int j = threadIdx.x; j < 2 * 1024; j += 256)
        if (h[j]) atomicAdd(&gh[j], h[j]);
}

// ---------------- single-block scan + rank search ----------------
__device__ void scan_search(const unsigned* __restrict__ gh, int NB, unsigned rank,
                            unsigned* sv, unsigned* wsb, unsigned* ret)
{
    const int tid = threadIdx.x;
    for (int j = tid; j < NB; j += 256) sv[j] = gh[j];
    __syncthreads();
    const int E = NB >> 8;
    const int base = tid * E;
    unsigned loc = 0u;
    for (int e = 0; e < E; ++e) loc += sv[base + e];
    unsigned inc = loc;
    const int lane = tid & 63;
    for (int off = 1; off < 64; off <<= 1) {
        unsigned u = __shfl_up(inc, off);
        if (lane >= off) inc += u;
    }
    const int wid = tid >> 6;
    if (lane == 63) wsb[wid] = inc;
    __syncthreads();
    if (tid == 0) {
        unsigned run = 0u;
        for (int w = 0; w < 4; ++w) { unsigned t = wsb[w]; wsb[w] = run; run += t; }
    }
    __syncthreads();
    unsigned c = wsb[wid] + (inc - loc);
    for (int e = 0; e < E; ++e) {
        unsigned hv = sv[base + e];
        if (rank >= c && rank < c + hv) { ret[0] = (unsigned)(base + e); ret[1] = rank - c; }
        c += hv;
    }
    __syncthreads();
}

extern "C" __global__ __launch_bounds__(256)
void k_scan1(unsigned* __restrict__ ws_u, float* __restrict__ ws_f,
             const unsigned* __restrict__ gh)
{
    __shared__ unsigned sv[2048];
    __shared__ unsigned wsb[4];
    __shared__ unsigned ret[2];
    __shared__ unsigned rk[2];
    if (threadIdx.x == 0) {
        int n = (int)ws_u[4];
        float nf = (float)(n - 1);
        float pos = fmaxf(0.75f * nf, 0.0f);
        float lo = floorf(pos);
        ws_f[7] = pos - lo;
        rk[0] = (unsigned)lo;
        rk[1] = (unsigned)ceilf(pos);
    }
    __syncthreads();
    unsigned r0 = rk[0], r1 = rk[1];
    scan_search(gh, 2048, r0, sv, wsb, ret);
    if (threadIdx.x == 0) { ws_u[8] = ret[0]; ws_u[10] = ret[1]; }
    scan_search(gh, 2048, r1, sv, wsb, ret);
    if (threadIdx.x == 0) { ws_u[9] = ret[0]; ws_u[11] = ret[1]; }
}

extern "C" __global__ __launch_bounds__(256)
void k_scan2(unsigned* __restrict__ ws_u, const unsigned* __restrict__ gh)
{
    __shared__ unsigned sv[2048];
    __shared__ unsigned wsb[4];
    __shared__ unsigned ret[2];
    unsigned p0 = ws_u[8], p1 = ws_u[9];
    unsigned r0 = ws_u[10], r1 = ws_u[11];
    scan_search(gh, 2048, r0, sv, wsb, ret);
    if (threadIdx.x == 0) { ws_u[8] = (p0 << 11) | ret[0]; ws_u[10] = ret[1]; }
    scan_search(gh + 2048, 2048, r1, sv, wsb, ret);
    if (threadIdx.x == 0) { ws_u[9] = (p1 << 11) | ret[0]; ws_u[11] = ret[1]; }
}

extern "C" __global__ __launch_bounds__(256)
void k_scan3(unsigned* __restrict__ ws_u, float* __restrict__ ws_f,
             const unsigned* __restrict__ gh)
{
    __shared__ unsigned sv[2048];
    __shared__ unsigned wsb[4];
    __shared__ unsigned ret[2];
    unsigned p0 = ws_u[8], p1 = ws_u[9];
    unsigned r0 = ws_u[10], r1 = ws_u[11];
    scan_search(gh, 1024, r0, sv, wsb, ret);
    float v0 = __uint_as_float((p0 << 10) | ret[0]);
    scan_search(gh + 1024, 1024, r1, sv, wsb, ret);
    float v1 = __uint_as_float((p1 << 10) | ret[0]);
    if (threadIdx.x == 0) {
        int n = (int)ws_u[4];
        float frac = ws_f[7];
        float q = v0 * (1.0f - frac) + v1 * frac;
        ws_f[6] = (n > 0) ? fmaxf(q, EPSF) : 1.0f;
    }
}

// ---------------- finalize ----------------
extern "C" __global__ __launch_bounds__(1024)
void k_final(const float* __restrict__ g_seg, const unsigned long long* __restrict__ ws_u64,
             const float* __restrict__ ws_f, const unsigned* __restrict__ ws_u,
             float* __restrict__ out)
{
    __shared__ double red[48];
    const double ref = (double)ws_f[6];
    const float4* gs4 = (const float4*)g_seg;   // interleaved per window
    double ninc = 0.0, fsum = 0.0, lsum = 0.0;
    for (int w = threadIdx.x; w < NWIN; w += blockDim.x) {
        float4 v = gs4[w];
        double c   = (double)v.x;
        double sp  = (double)v.y;
        double ar  = (double)v.z;
        double spd = (double)v.w;
        double inc = (c >= 2.0 && sp >= 1e-6) ? 1.0 : 0.0;
        double dmean = spd / (sp + 1e-6);
        double rr = ar / (1000.0 + 1e-6);
        double bu = fmax(rr - 1.0, 0.0);
        double flow = bu * bu;
        double rho = fmin(fmax(rr, 0.0), 0.99);
        double dth = 1.0 / (1.0 - rho + 1e-6);
        double lat = fmax(dth - dmean / ref, 0.0);
        ninc += inc; fsum += flow * inc; lsum += lat * inc;
    }
    for (int off = 32; off > 0; off >>= 1) {
        ninc += __shfl_down(ninc, off);
        fsum += __shfl_down(fsum, off);
        lsum += __shfl_down(lsum, off);
    }
    int wid = threadIdx.x >> 6, lane = threadIdx.x & 63;
    if (lane == 0) { red[wid] = ninc; red[16 + wid] = fsum; red[32 + wid] = lsum; }
    __syncthreads();
    if (threadIdx.x == 0) {
        double n_i = 0.0, f_s = 0.0, l_s = 0.0;
        int nw = (int)blockDim.x >> 6;
        for (int w = 0; w < nw; ++w) { n_i += red[w]; f_s += red[16 + w]; l_s += red[32 + w]; }
        double safe = fmax(n_i, 1.0);
        double l_flow = (n_i > 0.0) ? f_s / safe : 0.0;
        double l_lat  = (n_i > 0.0) ? l_s / safe : 0.0;
        double den = (double)ws_u64[1];
        double l_data = (den > 0.0) ? (double)ws_u64[0] / den : 0.0;
        bool any = ws_u[5] > 0u;
        if (!any) { l_data = 0.0; l_flow = 0.0; l_lat = 0.0; }
        out[0] = (float)(l_data + 0.1 * l_flow + 0.1 * l_lat);
        out[1] = (float)l_data;
        out[2] = (float)l_flow;
        out[3] = (float)l_lat;
    }
}

extern "C" void kernel_launch(void* const* d_in, const int* in_sizes, int n_in,
                              void* d_out, int out_size, void* d_ws, size_t ws_size,
                              hipStream_t stream)
{
    const float2* logits = (const float2*)d_in[0];
    const int* y = (const int*)d_in[1];
    const int* mask = (const int*)d_in[2];       // bool delivered as int32
    const float4* xraw = (const float4*)d_in[3];
    const int* widx = (const int*)d_in[4];
    const float* cw = (const float*)d_in[5];
    float* out = (float*)d_out;
    const int n = in_sizes[1];   // N from y

    unsigned char* ws8 = (unsigned char*)d_ws;
    unsigned long long* ws_u64 = (unsigned long long*)ws8;
    float* ws_f = (float*)ws8;
    unsigned* ws_u = (unsigned*)ws8;
    float* g_seg = (float*)(ws8 + OFF_SEG);
    unsigned* g_h1 = (unsigned*)(ws8 + OFF_H1);
    unsigned* g_h2 = (unsigned*)(ws8 + OFF_H2);
    unsigned* g_h3 = (unsigned*)(ws8 + OFF_H3);
    unsigned* g_seg_u32 = (unsigned*)(ws8 + OFF_SEGU);

    const size_t part_bytes = (size_t)GRID_SEG * 4 * NWIN * 4;   // 32 MB
    const size_t keys_bytes = (size_t)n * 4u;                    // 16.8 MB
    const size_t rec_bytes  = (size_t)n * 8u;                    // 33.5 MB
    size_t off = OFF_PART;
    int use_part = 0, use_keys = 0, use_rec = 0;
    unsigned* part = (unsigned*)(ws8 + off);
    if (ws_size >= off + part_bytes) { use_part = 1; off += part_bytes; }
    unsigned* keys = (unsigned*)(ws8 + off);
    if (ws_size >= off + keys_bytes) { use_keys = 1; off += keys_bytes; }
    unsigned long long* recs = (unsigned long long*)(ws8 + off);
    if (ws_size >= off + rec_bytes) { use_rec = 1; }

    hipMemsetAsync(d_ws, 0, OFF_PART, stream);   // header + g_seg(+u32) + hists

    k_ce_keys<<<1024, 256, 0, stream>>>(logits, y, mask, xraw, widx, cw,
                                        ws_u64, ws_u, keys, recs, g_h1,
                                        use_keys, use_rec, n);
    k_seg<<<GRID_SEG, BLOCK_SEG, 0, stream>>>(recs, logits, mask, xraw, widx,
                                              part, g_seg_u32, use_part, use_rec, n);
    if (use_part)
        k_reduce<<<256, 256, 0, stream>>>(part, g_seg_u32);
    k_convert<<<64, 256, 0, stream>>>(g_seg_u32, g_seg);
    k_scan1<<<1, 256, 0, stream>>>(ws_u, ws_f, g_h1);
    k_hist2<<<1024, 256, 0, stream>>>(keys, xraw, mask, widx, use_keys, n, ws_u, g_h2);
    k_scan2<<<1, 256, 0, stream>>>(ws_u, g_h2);
    k_hist3<<<1024, 256, 0, stream>>>(keys, xraw, mask, widx, use_keys, n, ws_u, g_h3);
    k_scan3<<<1, 256, 0, stream>>>(ws_u, ws_f, g_h3);
    k_final<<<1, 1024, 0, stream>>>(g_seg, ws_u64, ws_f, ws_u, out);
}

// Round 8
// 269.061 us; speedup vs baseline: 1.0673x; 1.0673x over previous
//
#include <hip/hip_runtime.h>

#define NWIN 4096
#define EPSF 1e-6f
#define GRID_MAIN 512
#define BLOCK_MAIN 512

// fixed-point scales (u32 LDS atomics; native ds_add_u32)
#define SCALE_P   2097152.0f     // 2^21  sum_p
#define SCALE_R   131072.0f      // 2^17  agg_rate / sum_pd
#define INV_P     (1.0/2097152.0)
#define INV_R     (1.0/131072.0)
#define SCALE_CE  1048576.0f     // 2^20  CE num/den (scales cancel)

// ---------------- workspace layout (bytes) ----------------
//  byte 0:  u64 ce_num        byte 8:  u64 ce_den
//  byte 16: u32 n_valid(u[4]) byte 20: u32 n_mask(u[5])
//  byte 24: f32 ref_dobs(f[6]) byte 28: f32 frac(f[7])
//  byte 32,36: u32 prefixes (u[8],u[9])  byte 40,44: u32 ranks (u[10],u[11])
#define OFF_SEG   256            // float g_seg[16384] interleaved [wi*4+c]
#define OFF_H1    65792          // u32[2048]
#define OFF_H2    73984          // u32[2*2048]
#define OFF_H3    90368          // u32[2*1024]
#define OFF_SEGU  131072         // u32 g_seg_u32[16384] interleaved
#define OFF_PART  262144         // GRID_MAIN x 64KB u32 partials; keys after

__device__ __forceinline__ unsigned make_key_raw(const float4* __restrict__ xraw,
                                                 const int* __restrict__ mask,
                                                 const int* __restrict__ widx, int i)
{
    int wi = widx[i];
    int m = mask[i];
    if (wi < 0 || !m) return 0x7F800000u;
    float d = fmaxf(xraw[i].z, 0.0f);
    unsigned k = __float_as_uint(d);
    return (k == 0x80000000u) ? 0u : k;
}

// ---------------- per-element fused work (interleaved s_seg [wi*4+c]) ----------------
__device__ __forceinline__ void process_elem(
    float lgx, float lgy, int yi, int mi, float xz, float xw, int wi,
    float cw0, float cw1, unsigned* keyOut,
    float& num, float& den, unsigned& nv, unsigned& nm, unsigned& zc,
    unsigned* s_seg, unsigned* s_h1)
{
    float wy = yi ? cw1 : cw0;
    float mx = fmaxf(lgx, lgy);
    float lse = mx + __logf(__expf(lgx - mx) + __expf(lgy - mx));
    float nll = lse - (yi ? lgy : lgx);
    if (mi) { nm++; num += wy * nll; den += wy; }

    bool vq = (wi >= 0) && mi;
    unsigned key = 0x7F800000u;
    if (vq) {
        nv++;
        float d = fmaxf(xz, 0.0f);
        key = __float_as_uint(d);
        if (key == 0x80000000u) key = 0u;
    }
    *keyOut = key;

    if (key == 0u) zc++;                    // huge tie at 0.0 stays in registers
    else atomicAdd(&s_h1[key >> 21], 1u);

    if (vq && wi < NWIN) {
        float p = 1.0f / (1.0f + __expf(lgx - lgy));
        float rate = fmaxf(xw, 0.0f);
        float dob  = fmaxf(xz, 0.0f);
        unsigned b = (unsigned)wi << 2;     // interleaved: 4 different banks
        atomicAdd(&s_seg[b], 1u);
        atomicAdd(&s_seg[b + 1], (unsigned)(p * SCALE_P + 0.5f));
        atomicAdd(&s_seg[b + 2], (unsigned)(p * rate * SCALE_R + 0.5f));
        atomicAdd(&s_seg[b + 3], (unsigned)(p * dob  * SCALE_R + 0.5f));
    }
}

struct Quad {
    float4 lgA, lgB;
    int4 y4, m4, w4;
    float4 x0, x1, x2, x3;
};

__device__ __forceinline__ Quad load_quad(const float4* __restrict__ lg4,
                                          const int4* __restrict__ y4p,
                                          const int4* __restrict__ m4p,
                                          const int4* __restrict__ w4p,
                                          const float4* __restrict__ xraw, int q)
{
    Quad t;
    t.lgA = lg4[2 * q]; t.lgB = lg4[2 * q + 1];
    t.y4 = y4p[q]; t.m4 = m4p[q]; t.w4 = w4p[q];
    t.x0 = xraw[4 * q]; t.x1 = xraw[4 * q + 1];
    t.x2 = xraw[4 * q + 2]; t.x3 = xraw[4 * q + 3];
    return t;
}

// ---------------- main fused pass: block-CONTIGUOUS chunks + 2-quad batching ----------------
extern "C" __global__ __launch_bounds__(BLOCK_MAIN, 4)
void k_main(const float2* __restrict__ logits, const int* __restrict__ y,
            const int* __restrict__ mask, const float4* __restrict__ xraw,
            const int* __restrict__ widx, const float* __restrict__ cw,
            unsigned long long* __restrict__ ws_u64, unsigned* __restrict__ ws_u,
            unsigned* __restrict__ g_seg_u32, unsigned* __restrict__ part,
            unsigned* __restrict__ keys, unsigned* __restrict__ gh1,
            int use_part, int use_keys, int n)
{
    __shared__ unsigned s_seg[4 * NWIN];   // 64 KB interleaved [wi*4+c]
    __shared__ unsigned s_h1[2048];        // 8 KB level-1 histogram
    for (int j = threadIdx.x; j < 4 * NWIN; j += BLOCK_MAIN) s_seg[j] = 0u;
    for (int j = threadIdx.x; j < 2048; j += BLOCK_MAIN) s_h1[j] = 0u;
    __syncthreads();

    const float cw0 = cw[0], cw1 = cw[1];
    float num = 0.0f, den = 0.0f;
    unsigned nv = 0u, nm = 0u, zc = 0u;

    const int nq = n >> 2;
    const int qpb = (nq + GRID_MAIN - 1) / GRID_MAIN;       // quads per block
    const int base = blockIdx.x * qpb;
    const int end = min(base + qpb, nq);

    const float4* lg4 = (const float4*)logits;
    const int4* y4p = (const int4*)y;
    const int4* m4p = (const int4*)mask;
    const int4* w4p = (const int4*)widx;

#define PROCESS_QUAD(T, Q)                                                        \
    do {                                                                          \
        uint4 kq;                                                                 \
        process_elem(T.lgA.x, T.lgA.y, T.y4.x, T.m4.x, T.x0.z, T.x0.w, T.w4.x,    \
                     cw0, cw1, &kq.x, num, den, nv, nm, zc, s_seg, s_h1);         \
        process_elem(T.lgA.z, T.lgA.w, T.y4.y, T.m4.y, T.x1.z, T.x1.w, T.w4.y,    \
                     cw0, cw1, &kq.y, num, den, nv, nm, zc, s_seg, s_h1);         \
        process_elem(T.lgB.x, T.lgB.y, T.y4.z, T.m4.z, T.x2.z, T.x2.w, T.w4.z,    \
                     cw0, cw1, &kq.z, num, den, nv, nm, zc, s_seg, s_h1);         \
        process_elem(T.lgB.z, T.lgB.w, T.y4.w, T.m4.w, T.x3.z, T.x3.w, T.w4.w,    \
                     cw0, cw1, &kq.w, num, den, nv, nm, zc, s_seg, s_h1);         \
        if (use_keys) ((uint4*)keys)[Q] = kq;                                     \
    } while (0)

    int q = base + threadIdx.x;
    while (q + BLOCK_MAIN < end) {
        // issue all 18 wide loads for two quads, then fence the scheduler so
        // the compiler cannot sink loads into the compute (keeps MLP)
        Quad A = load_quad(lg4, y4p, m4p, w4p, xraw, q);
        Quad B = load_quad(lg4, y4p, m4p, w4p, xraw, q + BLOCK_MAIN);
        __builtin_amdgcn_sched_barrier(0);
        PROCESS_QUAD(A, q);
        PROCESS_QUAD(B, q + BLOCK_MAIN);
        q += 2 * BLOCK_MAIN;
    }
    if (q < end) {
        Quad A = load_quad(lg4, y4p, m4p, w4p, xraw, q);
        __builtin_amdgcn_sched_barrier(0);
        PROCESS_QUAD(A, q);
    }
#undef PROCESS_QUAD

    // scalar tail (n % 4 != 0), grid-stride over the few leftover elements
    for (int i = (nq << 2) + blockIdx.x * BLOCK_MAIN + threadIdx.x; i < n;
         i += GRID_MAIN * BLOCK_MAIN) {
        float2 lg = logits[i];
        float4 xr = xraw[i];
        unsigned k;
        process_elem(lg.x, lg.y, y[i], mask[i], xr.z, xr.w, widx[i],
                     cw0, cw1, &k, num, den, nv, nm, zc, s_seg, s_h1);
        if (use_keys) keys[i] = k;
    }

    // wave(64) reduce, one global atomic per wave
    for (int off = 32; off > 0; off >>= 1) {
        num += __shfl_down(num, off);
        den += __shfl_down(den, off);
        nv  += __shfl_down(nv, off);
        nm  += __shfl_down(nm, off);
        zc  += __shfl_down(zc, off);
    }
    if ((threadIdx.x & 63) == 0) {
        atomicAdd(&ws_u64[0], (unsigned long long)(num * SCALE_CE + 0.5f));
        atomicAdd(&ws_u64[1], (unsigned long long)(den * SCALE_CE + 0.5f));
        atomicAdd(&ws_u[4], nv);
        atomicAdd(&ws_u[5], nm);
        if (zc) atomicAdd(&s_h1[0], zc);
    }
    __syncthreads();

    if (use_part) {
        uint4* dst = (uint4*)(part + (size_t)blockIdx.x * (4 * NWIN));
        const uint4* src = (const uint4*)s_seg;
        for (int j = threadIdx.x; j < NWIN; j += BLOCK_MAIN) dst[j] = src[j];
    } else {
        for (int j = threadIdx.x; j < 4 * NWIN; j += BLOCK_MAIN) {
            unsigned v = s_seg[j];
            if (v) atomicAdd(&g_seg_u32[j], v);
        }
    }
    for (int j = threadIdx.x; j < 2048; j += BLOCK_MAIN) {
        unsigned v = s_h1[j];
        if (v) atomicAdd(&gh1[j], v);
    }
}

// ---------------- partial reduction: 512 u32 partials -> g_seg_u32 ----------------
extern "C" __global__ __launch_bounds__(256)
void k_reduce(const unsigned* __restrict__ part, unsigned* __restrict__ g_seg_u32)
{
    const int bin = (blockIdx.x & 63) * 256 + threadIdx.x;
    const int c = blockIdx.x >> 6;
    const unsigned* p = part + (size_t)c * (GRID_MAIN / 4) * (4 * NWIN) + bin;
    unsigned s = 0u;
#pragma unroll 8
    for (int b = 0; b < GRID_MAIN / 4; ++b) s += p[(size_t)b * (4 * NWIN)];
    if (s) atomicAdd(&g_seg_u32[bin], s);
}

// convert u32 fixed-point sums to float g_seg (interleaved)
extern "C" __global__ __launch_bounds__(256)
void k_convert(const unsigned* __restrict__ gsu, float* __restrict__ g_seg)
{
    const int j = blockIdx.x * 256 + threadIdx.x;   // grid 64
    const int c = j & 3;
    double inv = (c == 0) ? 1.0 : (c == 1) ? INV_P : INV_R;
    g_seg[j] = (float)((double)gsu[j] * inv);
}

// ---------------- histogram passes 2 and 3 ----------------
__device__ __forceinline__ void h2_one(unsigned key, unsigned p0, unsigned p1,
                                       unsigned* h)
{
    unsigned top = key >> 21;
    unsigned sub = (key >> 10) & 2047u;
    if (top == p0) atomicAdd(&h[sub], 1u);
    if (top == p1) atomicAdd(&h[2048 + sub], 1u);
}

extern "C" __global__ __launch_bounds__(256)
void k_hist2(const unsigned* __restrict__ keys, const float4* __restrict__ xraw,
             const int* __restrict__ mask, const int* __restrict__ widx,
             int use_keys, int n, const unsigned* __restrict__ ws_u,
             unsigned* __restrict__ gh)
{
    __shared__ unsigned h[2 * 2048];
    for (int j = threadIdx.x; j < 2 * 2048; j += 256) h[j] = 0u;
    __syncthreads();
    const unsigned p0 = ws_u[8], p1 = ws_u[9];
    const int nthr = gridDim.x * blockDim.x;
    const int gtid = blockIdx.x * blockDim.x + threadIdx.x;
    const int nq = n >> 2;
    if (use_keys) {
        const uint4* k4 = (const uint4*)keys;
        int base = gtid;
        for (; base + 3 * nthr < nq; base += 4 * nthr) {
            uint4 a = k4[base], b = k4[base + nthr];
            uint4 c = k4[base + 2 * nthr], d = k4[base + 3 * nthr];
            h2_one(a.x, p0, p1, h); h2_one(a.y, p0, p1, h);
            h2_one(a.z, p0, p1, h); h2_one(a.w, p0, p1, h);
            h2_one(b.x, p0, p1, h); h2_one(b.y, p0, p1, h);
            h2_one(b.z, p0, p1, h); h2_one(b.w, p0, p1, h);
            h2_one(c.x, p0, p1, h); h2_one(c.y, p0, p1, h);
            h2_one(c.z, p0, p1, h); h2_one(c.w, p0, p1, h);
            h2_one(d.x, p0, p1, h); h2_one(d.y, p0, p1, h);
            h2_one(d.z, p0, p1, h); h2_one(d.w, p0, p1, h);
        }
        for (; base < nq; base += nthr) {
            uint4 a = k4[base];
            h2_one(a.x, p0, p1, h); h2_one(a.y, p0, p1, h);
            h2_one(a.z, p0, p1, h); h2_one(a.w, p0, p1, h);
        }
        for (int i = (nq << 2) + gtid; i < n; i += nthr)
            h2_one(keys[i], p0, p1, h);
    } else {
        for (int i = gtid; i < n; i += nthr)
            h2_one(make_key_raw(xraw, mask, widx, i), p0, p1, h);
    }
    __syncthreads();
    for (int j = threadIdx.x; j < 2 * 2048; j += 256)
        if (h[j]) atomicAdd(&gh[j], h[j]);
}

__device__ __forceinline__ void h3_one(unsigned key, unsigned p0, unsigned p1,
                                       unsigned* h)
{
    unsigned top = key >> 10;
    unsigned sub = key & 1023u;
    if (top == p0) atomicAdd(&h[sub], 1u);
    if (top == p1) atomicAdd(&h[1024 + sub], 1u);
}

extern "C" __global__ __launch_bounds__(256)
void k_hist3(const unsigned* __restrict__ keys, const float4* __restrict__ xraw,
             const int* __restrict__ mask, const int* __restrict__ widx,
             int use_keys, int n, const unsigned* __restrict__ ws_u,
             unsigned* __restrict__ gh)
{
    __shared__ unsigned h[2 * 1024];
    for (int j = threadIdx.x; j < 2 * 1024; j += 256) h[j] = 0u;
    __syncthreads();
    const unsigned p0 = ws_u[8], p1 = ws_u[9];
    const int nthr = gridDim.x * blockDim.x;
    const int gtid = blockIdx.x * blockDim.x + threadIdx.x;
    const int nq = n >> 2;
    if (use_keys) {
        const uint4* k4 = (const uint4*)keys;
        int base = gtid;
        for (; base + 3 * nthr < nq; base += 4 * nthr) {
            uint4 a = k4[base], b = k4[base + nthr];
            uint4 c = k4[base + 2 * nthr], d = k4[base + 3 * nthr];
            h3_one(a.x, p0, p1, h); h3_one(a.y, p0, p1, h);
            h3_one(a.z, p0, p1, h); h3_one(a.w, p0, p1, h);
            h3_one(b.x, p0, p1, h); h3_one(b.y, p0, p1, h);
            h3_one(b.z, p0, p1, h); h3_one(b.w, p0, p1, h);
            h3_one(c.x, p0, p1, h); h3_one(c.y, p0, p1, h);
            h3_one(c.z, p0, p1, h); h3_one(c.w, p0, p1, h);
            h3_one(d.x, p0, p1, h); h3_one(d.y, p0, p1, h);
            h3_one(d.z, p0, p1, h); h3_one(d.w, p0, p1, h);
        }
        for (; base < nq; base += nthr) {
            uint4 a = k4[base];
            h3_one(a.x, p0, p1, h); h3_one(a.y, p0, p1, h);
            h3_one(a.z, p0, p1, h); h3_one(a.w, p0, p1, h);
        }
        for (int i = (nq << 2) + gtid; i < n; i += nthr)
            h3_one(keys[i], p0, p1, h);
    } else {
        for (int i = gtid; i < n; i += nthr)
            h3_one(make_key_raw(xraw, mask, widx, i), p0, p1, h);
    }
    __syncthreads();
    for (int j = threadIdx.x; j < 2 * 1024; j += 256)
        if (h[j]) atomicAdd(&gh[j], h[j]);
}

// ---------------- single-block scan + rank search ----------------
__device__ void scan_search(const unsigned* __restrict__ gh, int NB, unsigned rank,
                            unsigned* sv, unsigned* wsb, unsigned* ret)
{
    const int tid = threadIdx.x;
    for (int j = tid; j < NB; j += 256) sv[j] = gh[j];
    __syncthreads();
    const int E = NB >> 8;
    const int base = tid * E;
    unsigned loc = 0u;
    for (int e = 0; e < E; ++e) loc += sv[base + e];
    unsigned inc = loc;
    const int lane = tid & 63;
    for (int off = 1; off < 64; off <<= 1) {
        unsigned u = __shfl_up(inc, off);
        if (lane >= off) inc += u;
    }
    const int wid = tid >> 6;
    if (lane == 63) wsb[wid] = inc;
    __syncthreads();
    if (tid == 0) {
        unsigned run = 0u;
        for (int w = 0; w < 4; ++w) { unsigned t = wsb[w]; wsb[w] = run; run += t; }
    }
    __syncthreads();
    unsigned c = wsb[wid] + (inc - loc);
    for (int e = 0; e < E; ++e) {
        unsigned hv = sv[base + e];
        if (rank >= c && rank < c + hv) { ret[0] = (unsigned)(base + e); ret[1] = rank - c; }
        c += hv;
    }
    __syncthreads();
}

extern "C" __global__ __launch_bounds__(256)
void k_scan1(unsigned* __restrict__ ws_u, float* __restrict__ ws_f,
             const unsigned* __restrict__ gh)
{
    __shared__ unsigned sv[2048];
    __shared__ unsigned wsb[4];
    __shared__ unsigned ret[2];
    __shared__ unsigned rk[2];
    if (threadIdx.x == 0) {
        int n = (int)ws_u[4];
        float nf = (float)(n - 1);
        float pos = fmaxf(0.75f * nf, 0.0f);
        float lo = floorf(pos);
        ws_f[7] = pos - lo;
        rk[0] = (unsigned)lo;
        rk[1] = (unsigned)ceilf(pos);
    }
    __syncthreads();
    unsigned r0 = rk[0], r1 = rk[1];
    scan_search(gh, 2048, r0, sv, wsb, ret);
    if (threadIdx.x == 0) { ws_u[8] = ret[0]; ws_u[10] = ret[1]; }
    scan_search(gh, 2048, r1, sv, wsb, ret);
    if (threadIdx.x == 0) { ws_u[9] = ret[0]; ws_u[11] = ret[1]; }
}

extern "C" __global__ __launch_bounds__(256)
void k_scan2(unsigned* __restrict__ ws_u, const unsigned* __restrict__ gh)
{
    __shared__ unsigned sv[2048];
    __shared__ unsigned wsb[4];
    __shared__ unsigned ret[2];
    unsigned p0 = ws_u[8], p1 = ws_u[9];
    unsigned r0 = ws_u[10], r1 = ws_u[11];
    scan_search(gh, 2048, r0, sv, wsb, ret);
    if (threadIdx.x == 0) { ws_u[8] = (p0 << 11) | ret[0]; ws_u[10] = ret[1]; }
    scan_search(gh + 2048, 2048, r1, sv, wsb, ret);
    if (threadIdx.x == 0) { ws_u[9] = (p1 << 11) | ret[0]; ws_u[11] = ret[1]; }
}

extern "C" __global__ __launch_bounds__(256)
void k_scan3(unsigned* __restrict__ ws_u, float* __restrict__ ws_f,
             const unsigned* __restrict__ gh)
{
    __shared__ unsigned sv[2048];
    __shared__ unsigned wsb[4];
    __shared__ unsigned ret[2];
    unsigned p0 = ws_u[8], p1 = ws_u[9];
    unsigned r0 = ws_u[10], r1 = ws_u[11];
    scan_search(gh, 1024, r0, sv, wsb, ret);
    float v0 = __uint_as_float((p0 << 10) | ret[0]);
    scan_search(gh + 1024, 1024, r1, sv, wsb, ret);
    float v1 = __uint_as_float((p1 << 10) | ret[0]);
    if (threadIdx.x == 0) {
        int n = (int)ws_u[4];
        float frac = ws_f[7];
        float q = v0 * (1.0f - frac) + v1 * frac;
        ws_f[6] = (n > 0) ? fmaxf(q, EPSF) : 1.0f;
    }
}

// ---------------- finalize ----------------
extern "C" __global__ __launch_bounds__(1024)
void k_final(const float* __restrict__ g_seg, const unsigned long long* __restrict__ ws_u64,
             const float* __restrict__ ws_f, const unsigned* __restrict__ ws_u,
             float* __restrict__ out)
{
    __shared__ double red[48];
    const double ref = (double)ws_f[6];
    const float4* gs4 = (const float4*)g_seg;   // interleaved per window
    double ninc = 0.0, fsum = 0.0, lsum = 0.0;
    for (int w = threadIdx.x; w < NWIN; w += blockDim.x) {
        float4 v = gs4[w];
        double c   = (double)v.x;
        double sp  = (double)v.y;
        double ar  = (double)v.z;
        double spd = (double)v.w;
        double inc = (c >= 2.0 && sp >= 1e-6) ? 1.0 : 0.0;
        double dmean = spd / (sp + 1e-6);
        double rr = ar / (1000.0 + 1e-6);
        double bu = fmax(rr - 1.0, 0.0);
        double flow = bu * bu;
        double rho = fmin(fmax(rr, 0.0), 0.99);
        double dth = 1.0 / (1.0 - rho + 1e-6);
        double lat = fmax(dth - dmean / ref, 0.0);
        ninc += inc; fsum += flow * inc; lsum += lat * inc;
    }
    for (int off = 32; off > 0; off >>= 1) {
        ninc += __shfl_down(ninc, off);
        fsum += __shfl_down(fsum, off);
        lsum += __shfl_down(lsum, off);
    }
    int wid = threadIdx.x >> 6, lane = threadIdx.x & 63;
    if (lane == 0) { red[wid] = ninc; red[16 + wid] = fsum; red[32 + wid] = lsum; }
    __syncthreads();
    if (threadIdx.x == 0) {
        double n_i = 0.0, f_s = 0.0, l_s = 0.0;
        int nw = (int)blockDim.x >> 6;
        for (int w = 0; w < nw; ++w) { n_i += red[w]; f_s += red[16 + w]; l_s += red[32 + w]; }
        double safe = fmax(n_i, 1.0);
        double l_flow = (n_i > 0.0) ? f_s / safe : 0.0;
        double l_lat  = (n_i > 0.0) ? l_s / safe : 0.0;
        double den = (double)ws_u64[1];
        double l_data = (den > 0.0) ? (double)ws_u64[0] / den : 0.0;
        bool any = ws_u[5] > 0u;
        if (!any) { l_data = 0.0; l_flow = 0.0; l_lat = 0.0; }
        out[0] = (float)(l_data + 0.1 * l_flow + 0.1 * l_lat);
        out[1] = (float)l_data;
        out[2] = (float)l_flow;
        out[3] = (float)l_lat;
    }
}

extern "C" void kernel_launch(void* const* d_in, const int* in_sizes, int n_in,
                              void* d_out, int out_size, void* d_ws, size_t ws_size,
                              hipStream_t stream)
{
    const float2* logits = (const float2*)d_in[0];
    const int* y = (const int*)d_in[1];
    const int* mask = (const int*)d_in[2];       // bool delivered as int32
    const float4* xraw = (const float4*)d_in[3];
    const int* widx = (const int*)d_in[4];
    const float* cw = (const float*)d_in[5];
    float* out = (float*)d_out;
    const int n = in_sizes[1];   // N from y

    unsigned char* ws8 = (unsigned char*)d_ws;
    unsigned long long* ws_u64 = (unsigned long long*)ws8;
    float* ws_f = (float*)ws8;
    unsigned* ws_u = (unsigned*)ws8;
    float* g_seg = (float*)(ws8 + OFF_SEG);
    unsigned* g_h1 = (unsigned*)(ws8 + OFF_H1);
    unsigned* g_h2 = (unsigned*)(ws8 + OFF_H2);
    unsigned* g_h3 = (unsigned*)(ws8 + OFF_H3);
    unsigned* g_seg_u32 = (unsigned*)(ws8 + OFF_SEGU);

    const size_t part_bytes = (size_t)GRID_MAIN * 4 * NWIN * 4;  // 32 MB
    const size_t keys_bytes = (size_t)n * 4u;                    // 16.8 MB
    size_t off = OFF_PART;
    int use_part = 0, use_keys = 0;
    unsigned* part = (unsigned*)(ws8 + off);
    if (ws_size >= off + part_bytes) { use_part = 1; off += part_bytes; }
    unsigned* keys = (unsigned*)(ws8 + off);
    if (ws_size >= off + keys_bytes) { use_keys = 1; }

    hipMemsetAsync(d_ws, 0, OFF_PART, stream);   // header + g_seg(+u32) + hists

    k_main<<<GRID_MAIN, BLOCK_MAIN, 0, stream>>>(logits, y, mask, xraw, widx, cw,
                                                 ws_u64, ws_u, g_seg_u32, part, keys,
                                                 g_h1, use_part, use_keys, n);
    if (use_part)
        k_reduce<<<256, 256, 0, stream>>>(part, g_seg_u32);
    k_convert<<<64, 256, 0, stream>>>(g_seg_u32, g_seg);
    k_scan1<<<1, 256, 0, stream>>>(ws_u, ws_f, g_h1);
    k_hist2<<<1024, 256, 0, stream>>>(keys, xraw, mask, widx, use_keys, n, ws_u, g_h2);
    k_scan2<<<1, 256, 0, stream>>>(ws_u, g_h2);
    k_hist3<<<1024, 256, 0, stream>>>(keys, xraw, mask, widx, use_keys, n, ws_u, g_h3);
    k_scan3<<<1, 256, 0, stream>>>(ws_u, ws_f, g_h3);
    k_final<<<1, 1024, 0, stream>>>(g_seg, ws_u64, ws_f, ws_u, out);
}